// Round 7
// baseline (143.663 us; speedup 1.0000x reference)
//
#include <hip/hip_runtime.h>
#include <hip/hip_bf16.h>
#include <math.h>

#define T_DIM 2048
#define B_DIM 2
#define E_DIM 1024
#define H_DIM 16
#define HD_DIM 64
#define M_DIM (T_DIM * B_DIM)   // 4096 rows (t*B+b)
#define BH_DIM (B_DIM * H_DIM)  // 32 head-batches

using bf16x8 = __attribute__((ext_vector_type(8))) __bf16;
using u16x8  = __attribute__((ext_vector_type(8))) unsigned short;
using u16x4  = __attribute__((ext_vector_type(4))) unsigned short;
using f32x4  = __attribute__((ext_vector_type(4))) float;

static __device__ __forceinline__ unsigned short f2bf(float f) {
  unsigned u = __builtin_bit_cast(unsigned, f);
  u += 0x7fff + ((u >> 16) & 1);   // RNE
  return (unsigned short)(u >> 16);
}

__device__ __forceinline__ void gload_lds16(const void* g, void* l) {
  __builtin_amdgcn_global_load_lds(
      (const __attribute__((address_space(1))) unsigned int*)g,
      (__attribute__((address_space(3))) unsigned int*)l, 16, 0, 0);
}

// ---------------- fp32 -> bf16 cast (both weights, one launch) -------------
__global__ __launch_bounds__(256) void cast2_kernel(
    const float* __restrict__ in1, unsigned short* __restrict__ out1, int n1,
    const float* __restrict__ in2, unsigned short* __restrict__ out2, int n2) {
  int i = blockIdx.x * 256 + threadIdx.x;
  const float* in; unsigned short* out; int idx;
  if (i < n1) { in = in1; out = out1; idx = i; }
  else if (i < n1 + n2) { in = in2; out = out2; idx = i - n1; }
  else return;
  float4 v = ((const float4*)in)[idx];
  ushort4 o;
  o.x = f2bf(v.x); o.y = f2bf(v.y); o.z = f2bf(v.z); o.w = f2bf(v.w);
  ((ushort4*)out)[idx] = o;
}

// ---------------- LayerNorm (row = one block) ----------------
__global__ __launch_bounds__(256) void ln_kernel(
    const float* __restrict__ q, const float* __restrict__ gamma,
    const float* __restrict__ beta, unsigned short* __restrict__ out) {
  int row = blockIdx.x;
  int tid = threadIdx.x;
  const float4* qr = (const float4*)(q + (size_t)row * E_DIM);
  float4 x = qr[tid];
  float s  = x.x + x.y + x.z + x.w;
  float ss = x.x * x.x + x.y * x.y + x.z * x.z + x.w * x.w;
#pragma unroll
  for (int off = 32; off >= 1; off >>= 1) {
    s  += __shfl_xor(s, off, 64);
    ss += __shfl_xor(ss, off, 64);
  }
  __shared__ float red[8];
  int wid = tid >> 6, lane = tid & 63;
  if (lane == 0) { red[wid] = s; red[4 + wid] = ss; }
  __syncthreads();
  s  = red[0] + red[1] + red[2] + red[3];
  ss = red[4] + red[5] + red[6] + red[7];
  float mean = s * (1.0f / E_DIM);
  float var  = ss * (1.0f / E_DIM) - mean * mean;
  float rstd = rsqrtf(var + 1e-5f);
  float4 g4 = ((const float4*)gamma)[tid];
  float4 b4 = ((const float4*)beta)[tid];
  ushort4 o;
  o.x = f2bf((x.x - mean) * rstd * g4.x + b4.x);
  o.y = f2bf((x.y - mean) * rstd * g4.y + b4.y);
  o.z = f2bf((x.z - mean) * rstd * g4.z + b4.z);
  o.w = f2bf((x.w - mean) * rstd * g4.w + b4.w);
  ((ushort4*)(out + (size_t)row * E_DIM))[tid] = o;
}

// ---------------- GEMM: C[M,N] = A[M,K] * Bw[N,K]^T (bf16 in, fp32 acc) ----
// MODE 0: q -> out_q [bh][t][64]; k -> out_pk fragment-packed
//         [bh][tile][cf*2+ks][lane][8]; v -> out_v [bh][t][64]
// MODE 1: out_f = resid + C (fp32)
template <int MODE>
__global__ __launch_bounds__(256) void gemm_bt_kernel(
    const unsigned short* __restrict__ A, const unsigned short* __restrict__ Bw,
    const float* __restrict__ resid, unsigned short* __restrict__ out_q,
    unsigned short* __restrict__ out_pk, unsigned short* __restrict__ out_v,
    float* __restrict__ out_f, int Kv, int Nv) {
  __shared__ alignas(16) unsigned short lA[128 * 32];
  __shared__ alignas(16) unsigned short lB[128 * 32];
  int tid = threadIdx.x;
  int wid = tid >> 6, lane = tid & 63;
  int wm = wid >> 1, wn = wid & 1;
  int g = lane >> 4, lr = lane & 15;
  int m0 = blockIdx.y * 128, n0 = blockIdx.x * 128;
  f32x4 acc[4][4] = {};

  for (int k0 = 0; k0 < Kv; k0 += 32) {
#pragma unroll
    for (int c = 0; c < 2; ++c) {
      int f16 = c * 256 + tid;
      int row = f16 >> 2, col8 = (f16 & 3) << 3;
      gload_lds16(A  + (size_t)(m0 + row) * Kv + k0 + col8,
                  lA + (size_t)(c * 256 + wid * 64) * 8);
      gload_lds16(Bw + (size_t)(n0 + row) * Kv + k0 + col8,
                  lB + (size_t)(c * 256 + wid * 64) * 8);
    }
    __syncthreads();
    bf16x8 af[4], bfr[4];
#pragma unroll
    for (int r = 0; r < 4; ++r) {
      af[r]  = *(const bf16x8*)(lA + (wm * 64 + r * 16 + lr) * 32 + g * 8);
      bfr[r] = *(const bf16x8*)(lB + (wn * 64 + r * 16 + lr) * 32 + g * 8);
    }
#pragma unroll
    for (int mr = 0; mr < 4; ++mr)
#pragma unroll
      for (int nr = 0; nr < 4; ++nr)
        acc[mr][nr] = __builtin_amdgcn_mfma_f32_16x16x32_bf16(
            af[mr], bfr[nr], acc[mr][nr], 0, 0, 0);
    __syncthreads();
  }

#pragma unroll
  for (int mr = 0; mr < 4; ++mr) {
#pragma unroll
    for (int nr = 0; nr < 4; ++nr) {
#pragma unroll
      for (int r = 0; r < 4; ++r) {
        int grow = m0 + wm * 64 + mr * 16 + g * 4 + r;
        int gcol = n0 + wn * 64 + nr * 16 + lr;
        float v = acc[mr][nr][r];
        if (MODE == 0) {
          int which = gcol >> 10, rem = gcol & 1023;
          int h = rem >> 6, d = rem & 63;
          int t = grow >> 1, b = grow & 1;
          size_t bh = (size_t)(b * H_DIM + h);
          if (which == 0) {
            out_q[(bh * T_DIM + t) * HD_DIM + d] = f2bf(v);
          } else if (which == 1) {
            int tile = t >> 6, trow = t & 63;
            int cf = trow >> 4, ks = d >> 5;
            int plane = ((d >> 3) & 3) * 16 + (trow & 15);
            out_pk[bh * (32 * 8 * 512) +
                   (size_t)((tile * 8) + cf * 2 + ks) * 512 + plane * 8 + (d & 7)]
                = f2bf(v);
          } else {
            out_v[(bh * T_DIM + t) * HD_DIM + d] = f2bf(v);
          }
        } else {
          size_t idx = (size_t)grow * Nv + gcol;
          out_f[idx] = resid[idx] + v;
        }
      }
    }
  }
}

// ---------------- V pack: [bh][t][d] -> fragment blobs --------------------
// pv[bh][tile][df*2+ks][lane][j] = V[bh][tile*64 + pi^-1(ks*32+(lane>>4)*8+j)]
//                                   [df*16 + (lane&15)],  pi^-1(p)=((p&3)<<4)|(p>>2)
__global__ __launch_bounds__(256) void pack_v_kernel(
    const unsigned short* __restrict__ vb, unsigned short* __restrict__ pv) {
  __shared__ alignas(16) unsigned short lV[64 * 72];
  int tid = threadIdx.x;
  int wid = tid >> 6, lane = tid & 63;
  int tile = blockIdx.x, bh = blockIdx.y;
  const unsigned short* src = vb + ((size_t)bh * T_DIM + tile * 64) * HD_DIM;
#pragma unroll
  for (int e = 0; e < 2; ++e) {
    int i8 = e * 256 + tid;
    int r = i8 >> 3, c = (i8 & 7) * 8;
    *(bf16x8*)(lV + r * 72 + c) = *(const bf16x8*)(src + (size_t)r * HD_DIM + c);
  }
  __syncthreads();
  unsigned short* dst = pv + ((size_t)bh * 32 + tile) * (8 * 512);
#pragma unroll
  for (int q = 0; q < 2; ++q) {
    int bv = wid * 2 + q;
    int df = bv >> 1, ks = bv & 1;
    u16x8 o;
#pragma unroll
    for (int j = 0; j < 8; ++j) {
      int p = ks * 32 + (lane >> 4) * 8 + j;
      int tl = ((p & 3) << 4) | (p >> 2);
      o[j] = lV[tl * 72 + df * 16 + (lane & 15)];
    }
    *(u16x8*)(dst + (size_t)bv * 512 + lane * 8) = o;
  }
}

// ---------------- Flash attention v2: barrier-free, fragment-packed -------
// 2 waves/block, 32 q-rows/wave, 64 q-rows/block; grid 1024 (XCD-swizzled so
// each XCD owns 4 bh -> K/V L2-resident). K/V read as coalesced 1KB fragment
// blobs from global; no shared K/V LDS -> NO barriers. P goes through
// per-wave LDS (packed u16x4, pi k-order matching packed V).
// Softmax: P = 2^(qk*QS - 8), fixed max (exact; scale cancels in accO/accS);
// row-sum via ones-MFMA.
__global__ __launch_bounds__(128) void attn_kernel(
    const unsigned short* __restrict__ qb, const unsigned short* __restrict__ pk,
    const unsigned short* __restrict__ pv, unsigned short* __restrict__ ctx) {
  __shared__ alignas(16) unsigned short lP[2][32 * 72];
  int tid = threadIdx.x;
  int wid = tid >> 6, lane = tid & 63;
  int g = lane >> 4, lr = lane & 15;
  int f = blockIdx.x;                 // 0..1023
  int xcd = f & 7, k2 = f >> 3;
  int bh = xcd + 8 * (k2 & 3);        // 4 bh per XCD
  int qt = k2 >> 2;                   // 0..31 (64-row q-tiles)
  int b = bh >> 4, h = bh & 15;
  const size_t koff = (size_t)bh * T_DIM * HD_DIM;
  const unsigned short* pkb = pk + (size_t)bh * (32 * 8 * 512);
  const unsigned short* pvb = pv + (size_t)bh * (32 * 8 * 512);

  // Q fragments (32 rows/wave), scale 1/8 * log2(e) folded in
  bf16x8 qf[2][2];
  {
    const float QS = 0.125f * 1.44269504f;
#pragma unroll
    for (int qa = 0; qa < 2; ++qa) {
      int qrow = qt * 64 + wid * 32 + qa * 16 + lr;
#pragma unroll
      for (int ks = 0; ks < 2; ++ks) {
        bf16x8 raw = *(const bf16x8*)(qb + koff + (size_t)qrow * HD_DIM + ks * 32 + g * 8);
#pragma unroll
        for (int j = 0; j < 8; ++j) qf[qa][ks][j] = (__bf16)((float)raw[j] * QS);
      }
    }
  }

  bf16x8 onesf;
#pragma unroll
  for (int j = 0; j < 8; ++j) onesf[j] = (__bf16)1.0f;

  f32x4 accO[2][4] = {};
  f32x4 accS[2] = {};

  bf16x8 kfa[8], kfb[8];
#pragma unroll
  for (int bk = 0; bk < 8; ++bk)
    kfa[bk] = *(const bf16x8*)(pkb + (size_t)bk * 512 + lane * 8);

#define ITER(KC, KN, T, LAST)                                                  \
  do {                                                                         \
    bf16x8 vf[8];                                                              \
    _Pragma("unroll")                                                          \
    for (int bv = 0; bv < 8; ++bv)                                             \
      vf[bv] = *(const bf16x8*)(pvb + ((size_t)(T) * 8 + bv) * 512 + lane * 8);\
    f32x4 s4[2][4];                                                            \
    __builtin_amdgcn_s_setprio(1);                                             \
    _Pragma("unroll")                                                          \
    for (int cf = 0; cf < 4; ++cf) {                                           \
      _Pragma("unroll")                                                        \
      for (int qa = 0; qa < 2; ++qa) {                                         \
        f32x4 s = {-8.0f, -8.0f, -8.0f, -8.0f};                                \
        s = __builtin_amdgcn_mfma_f32_16x16x32_bf16(qf[qa][0], KC[cf * 2 + 0], s, 0, 0, 0); \
        s = __builtin_amdgcn_mfma_f32_16x16x32_bf16(qf[qa][1], KC[cf * 2 + 1], s, 0, 0, 0); \
        s4[qa][cf] = s;                                                        \
      }                                                                        \
    }                                                                          \
    __builtin_amdgcn_s_setprio(0);                                             \
    if (!(LAST)) {                                                             \
      _Pragma("unroll")                                                        \
      for (int bk = 0; bk < 8; ++bk)                                           \
        KN[bk] = *(const bf16x8*)(pkb + ((size_t)((T) + 1) * 8 + bk) * 512 + lane * 8); \
    }                                                                          \
    _Pragma("unroll")                                                          \
    for (int qa = 0; qa < 2; ++qa)                                             \
      _Pragma("unroll")                                                        \
      for (int r = 0; r < 4; ++r) {                                            \
        u16x4 pkv;                                                             \
        _Pragma("unroll")                                                      \
        for (int cf = 0; cf < 4; ++cf)                                         \
          pkv[cf] = __builtin_bit_cast(unsigned short,                         \
                      (__bf16)__builtin_amdgcn_exp2f(s4[qa][cf][r]));          \
        *(u16x4*)(&lP[wid][(qa * 16 + g * 4 + r) * 72 + lr * 4]) = pkv;        \
      }                                                                        \
    __builtin_amdgcn_s_setprio(1);                                             \
    _Pragma("unroll")                                                          \
    for (int ks = 0; ks < 2; ++ks) {                                           \
      bf16x8 pf[2];                                                            \
      _Pragma("unroll")                                                        \
      for (int qa = 0; qa < 2; ++qa) {                                         \
        pf[qa] = *(const bf16x8*)(&lP[wid][(qa * 16 + lr) * 72 + ks * 32 + g * 8]); \
        accS[qa] = __builtin_amdgcn_mfma_f32_16x16x32_bf16(pf[qa], onesf, accS[qa], 0, 0, 0); \
      }                                                                        \
      _Pragma("unroll")                                                        \
      for (int df = 0; df < 4; ++df) {                                         \
        _Pragma("unroll")                                                      \
        for (int qa = 0; qa < 2; ++qa)                                         \
          accO[qa][df] = __builtin_amdgcn_mfma_f32_16x16x32_bf16(pf[qa], vf[df * 2 + ks], accO[qa][df], 0, 0, 0); \
      }                                                                        \
    }                                                                          \
    __builtin_amdgcn_s_setprio(0);                                             \
  } while (0)

  for (int t2 = 0; t2 < 32; t2 += 2) {
    ITER(kfa, kfb, t2, false);
    ITER(kfb, kfa, t2 + 1, t2 + 1 == 31);
  }
#undef ITER

  // ctx[t*B+b][h*64+d] bf16
#pragma unroll
  for (int qa = 0; qa < 2; ++qa) {
    float invl[4];
#pragma unroll
    for (int r = 0; r < 4; ++r) invl[r] = 1.0f / accS[qa][r];
#pragma unroll
    for (int df = 0; df < 4; ++df) {
#pragma unroll
      for (int r = 0; r < 4; ++r) {
        int t = qt * 64 + wid * 32 + qa * 16 + g * 4 + r;
        int col = h * HD_DIM + df * 16 + lr;
        float o = accO[qa][df][r] * invl[r];
        ctx[((size_t)t * B_DIM + b) * E_DIM + col] = f2bf(o);
      }
    }
  }
}

// ---------------- launcher ----------------
extern "C" void kernel_launch(void* const* d_in, const int* in_sizes, int n_in,
                              void* d_out, int out_size, void* d_ws, size_t ws_size,
                              hipStream_t stream) {
  const float* query = (const float*)d_in[0];
  const float* gamma = (const float*)d_in[1];
  const float* beta  = (const float*)d_in[2];
  const float* w_in  = (const float*)d_in[3];
  const float* w_out = (const float*)d_in[4];
  float* out = (float*)d_out;

  unsigned short* ws    = (unsigned short*)d_ws;
  unsigned short* ln    = ws;                                 // 4096*1024
  unsigned short* winb  = ln + (size_t)M_DIM * E_DIM;         // 3072*1024
  unsigned short* woutb = winb + (size_t)3 * E_DIM * E_DIM;   // 1024*1024
  unsigned short* qbuf  = woutb + (size_t)E_DIM * E_DIM;      // 32*2048*64
  unsigned short* vbuf  = qbuf + (size_t)BH_DIM * T_DIM * HD_DIM;
  unsigned short* pk    = vbuf + (size_t)BH_DIM * T_DIM * HD_DIM;
  unsigned short* pv    = ln;    // reuse: ln consumed by GEMM0 before pack_v
  unsigned short* ctx   = vbuf;  // reuse: vbuf consumed by pack_v before attn

  cast2_kernel<<<dim3(4096), dim3(256), 0, stream>>>(
      w_in, winb, 3 * E_DIM * E_DIM / 4, w_out, woutb, E_DIM * E_DIM / 4);
  ln_kernel<<<dim3(M_DIM), dim3(256), 0, stream>>>(query, gamma, beta, ln);
  gemm_bt_kernel<0><<<dim3(3 * E_DIM / 128, M_DIM / 128), dim3(256), 0, stream>>>(
      ln, winb, nullptr, qbuf, pk, vbuf, nullptr, E_DIM, 3 * E_DIM);
  pack_v_kernel<<<dim3(T_DIM / 64, BH_DIM), dim3(256), 0, stream>>>(vbuf, pv);
  attn_kernel<<<dim3(1024), dim3(128), 0, stream>>>(qbuf, pk, pv, ctx);
  gemm_bt_kernel<1><<<dim3(E_DIM / 128, M_DIM / 128), dim3(256), 0, stream>>>(
      ctx, woutb, query, nullptr, nullptr, nullptr, out, E_DIM, E_DIM);
}